// Round 5
// baseline (145.168 us; speedup 1.0000x reference)
//
#include <hip/hip_runtime.h>
#include <cstddef>

#define HOP 256
#define NSTFT 513
#define N_MELS 80
#define T_AUDIO 320000
#define NUM_FRAMES 1251
#define NBATCH 16
#define TOTAL_FRAMES (NBATCH * NUM_FRAMES)  // 20016 = 2502 blocks * 2 waves * 4 frames

// Slaney mel constants
#define LOGSTEP 0.06875177742094913f
#define MEL_MAX 45.24564047f
#define DF 15.625f

__device__ __forceinline__ int reflect_idx(int j) {
    j = (j < 0) ? -j : j;
    j = (j >= T_AUDIO) ? (2 * T_AUDIO - 2 - j) : j;
    return j;
}

// DPP cross-lane exchange (VALU pipe) for xor 1/2/8
#define DPP_XOR1 0xB1   // quad_perm [1,0,3,2]
#define DPP_XOR2 0x4E   // quad_perm [2,3,0,1]
#define DPP_XOR8 0x128  // row_ror:8
template<int CTRL>
__device__ __forceinline__ float dppf(float x) {
    return __int_as_float(__builtin_amdgcn_update_dpp(
        0, __float_as_int(x), CTRL, 0xF, 0xF, true));
}

template<class F>
__device__ __forceinline__ void cstage(float (&zr)[2][16], float (&zi)[2][16],
                                       float sg, float twr_, float twi_, F comm) {
    #pragma unroll
    for (int p = 0; p < 2; ++p) {
        #pragma unroll
        for (int r = 0; r < 16; ++r) {
            const float pr  = comm(zr[p][r]);
            const float pim = comm(zi[p][r]);
            const float qr = fmaf(sg, zr[p][r], pr);
            const float qi = fmaf(sg, zi[p][r], pim);
            zr[p][r] = fmaf(qr, twr_, -(qi * twi_));
            zi[p][r] = fmaf(qr, twi_, qi * twr_);
        }
    }
}

// 2 waves/block, 4 frames/wave. Four-step 1024-pt FFT (16 regs x 64 lanes),
// real-packed (2 frames per complex FFT). Mel matmul inverted to per-bin
// scatter: bin k feeds exactly 2 mels (m1, m1-1); weights staged once per
// block in a swizzled LDS table (from fb), accumulation via ds_add_f32 into
// per-wave smel[4][80]. Coalesced transposed epilogue per block.
__global__ __launch_bounds__(128) void melspec_scatter_kernel(
    const float* __restrict__ wav,     // 16 x 320000
    const float* __restrict__ window,  // 1024
    const float* __restrict__ fb,      // 513 x 80
    const float* __restrict__ cosT,    // 1024 x 513 (row1 = cos(2pi j/1024))
    const float* __restrict__ sinT,    // 1024 x 513 (row1 = -sin(2pi j/1024))
    float* __restrict__ out)           // 16 x 80 x 1251
{
    __shared__ float2 wtab[NSTFT];       // (0.5*w_up, 0.5*w_down | m1 in low 7 bits)
    __shared__ float  smel[2][4][N_MELS];

    const int tid = threadIdx.x;
    const int lane = tid & 63;
    const int w = tid >> 6;
    const int g0 = blockIdx.x * 8 + w * 4;

    const int BREV4[16] = {0,8,4,12,2,10,6,14,1,9,5,13,3,11,7,15};
    const int SIG[16]   = {0,1,3,2,7,6,5,4,15,14,13,12,11,10,9,8};
    const float W16R[8] = {1.0f, 0.92387953251128674f, 0.70710678118654752f, 0.38268343236508977f,
                           0.0f, -0.38268343236508977f, -0.70710678118654752f, -0.92387953251128674f};
    const float W16I[8] = {0.0f, -0.38268343236508977f, -0.70710678118654752f, -0.92387953251128674f,
                           -1.0f, -0.92387953251128674f, -0.70710678118654752f, -0.38268343236508977f};

    // ---- per-block weight table: bin k -> (0.5*wu, 0.5*wd, m1) ----
    for (int k = tid; k < NSTFT; k += 128) {
        const float f = k * DF;
        const float mel = (f < 1000.f) ? (3.0f / 200.0f) * f
                                       : 15.0f + logf(f * 1e-3f) * (1.0f / LOGSTEP);
        const int m1 = (int)floorf(mel * (81.0f / MEL_MAX));   // 0..81
        const float wu = (m1 <= 79) ? 0.5f * fb[k * N_MELS + m1] : 0.0f;
        const float wd = (m1 >= 1 && m1 <= 80) ? 0.5f * fb[k * N_MELS + m1 - 1] : 0.0f;
        const unsigned mp = (unsigned)min(m1, 80);
        const unsigned u = (__float_as_uint(wd) & ~127u) | mp;
        const int slot = (k & ~15) | (((k >> 4) ^ k) & 15);
        wtab[slot] = make_float2(wu, __uint_as_float(u));
    }
    // ---- zero own mel accumulators ----
    #pragma unroll
    for (int i = 0; i < 5; ++i) ((float*)smel[w])[lane + 64 * i] = 0.0f;
    __syncthreads();

    unsigned bf0, ff0, bf3;
    {
        const unsigned g = (unsigned)g0;
        bf0 = g / NUM_FRAMES; ff0 = g - bf0 * NUM_FRAMES;
        bf3 = (unsigned)(g0 + 3) / NUM_FRAMES;
    }

    // ---- window ----
    float win[16];
    #pragma unroll
    for (int r = 0; r < 16; ++r) win[r] = window[r * 64 + lane];

    // ---- load 4 frames (75%-overlap shared-chunk fast path) ----
    float zr[2][16], zi[2][16];
    if (bf0 == bf3) {
        const float* wb = wav + (size_t)bf0 * T_AUDIO;
        const int base = (int)ff0 * HOP - 512;
        float ch[28];
        #pragma unroll
        for (int c = 0; c < 28; ++c)
            ch[c] = wb[reflect_idx(base + c * 64 + lane)];
        #pragma unroll
        for (int r = 0; r < 16; ++r) {
            zr[0][r] = ch[r]      * win[r];
            zi[0][r] = ch[r + 4]  * win[r];
            zr[1][r] = ch[r + 8]  * win[r];
            zi[1][r] = ch[r + 12] * win[r];
        }
    } else {
        #pragma unroll
        for (int fi = 0; fi < 4; ++fi) {
            const unsigned g = (unsigned)(g0 + fi);
            const unsigned bb = g / NUM_FRAMES;
            const unsigned ffr = g - bb * NUM_FRAMES;
            const float* wb = wav + (size_t)bb * T_AUDIO;
            const int base = (int)ffr * HOP - 512;
            #pragma unroll
            for (int r = 0; r < 16; ++r) {
                const float v = wb[reflect_idx(base + r * 64 + lane)] * win[r];
                if (fi == 0) zr[0][r] = v;
                else if (fi == 1) zi[0][r] = v;
                else if (fi == 2) zr[1][r] = v;
                else zi[1][r] = v;
            }
        }
    }

    const float* twc = cosT + NSTFT;  // row n=1
    const float* tws = sinT + NSTFT;

    // ---- cross twiddles: wk[k] = W_1024^(lane*k) via complex powers ----
    const float w1r = twc[lane];
    const float w1i = tws[lane];
    float wkr[16], wki[16];
    wkr[0] = 1.0f; wki[0] = 0.0f;
    #pragma unroll
    for (int k = 1; k < 16; ++k) {
        wkr[k] = wkr[k-1] * w1r - wki[k-1] * w1i;
        wki[k] = wkr[k-1] * w1i + wki[k-1] * w1r;
    }

    // ---- stage twiddles for cross-lane FFT ----
    float c64[6], s64[6];
    #pragma unroll
    for (int t = 0; t < 6; ++t) {
        const int half = 32 >> t;
        const bool hi = (lane & half) != 0;
        const int jj = (lane & (half - 1)) << (t + 4);
        c64[t] = hi ? twc[jj] : 1.0f;
        s64[t] = hi ? tws[jj] : 0.0f;
    }

    // ---- A) 16-pt DIF FFT in registers ----
    #define CBFLY(ar, ai, br, bi, wr, wi) { \
        const float _tr = (ar) - (br), _ti = (ai) - (bi); \
        (ar) += (br); (ai) += (bi); \
        (br) = _tr * (wr) - _ti * (wi); \
        (bi) = _tr * (wi) + _ti * (wr); }

    #pragma unroll
    for (int p = 0; p < 2; ++p) {
        #pragma unroll
        for (int q = 0; q < 8; ++q) CBFLY(zr[p][q], zi[p][q], zr[p][q+8], zi[p][q+8], W16R[q], W16I[q]);
        #pragma unroll
        for (int g = 0; g < 16; g += 8)
            #pragma unroll
            for (int q = 0; q < 4; ++q) CBFLY(zr[p][g+q], zi[p][g+q], zr[p][g+q+4], zi[p][g+q+4], W16R[2*q], W16I[2*q]);
        #pragma unroll
        for (int g = 0; g < 16; g += 4)
            #pragma unroll
            for (int q = 0; q < 2; ++q) CBFLY(zr[p][g+q], zi[p][g+q], zr[p][g+q+2], zi[p][g+q+2], W16R[4*q], W16I[4*q]);
        #pragma unroll
        for (int g = 0; g < 16; g += 2) CBFLY(zr[p][g], zi[p][g], zr[p][g+1], zi[p][g+1], 1.0f, 0.0f);
    }

    // ---- B) cross twiddle ----
    #pragma unroll
    for (int r = 1; r < 16; ++r) {
        const float c1 = wkr[BREV4[r]];
        const float s1 = wki[BREV4[r]];
        #pragma unroll
        for (int p = 0; p < 2; ++p) {
            const float xr = zr[p][r], xi = zi[p][r];
            zr[p][r] = xr * c1 - xi * s1;
            zi[p][r] = xr * s1 + xi * c1;
        }
    }

    // ---- C) 64-pt DIF FFT across lanes ----
    {
        float sg;
        sg = (lane & 32) ? -1.0f : 1.0f;
        cstage(zr, zi, sg, c64[0], s64[0], [](float v) { return __shfl_xor(v, 32); });
        sg = (lane & 16) ? -1.0f : 1.0f;
        cstage(zr, zi, sg, c64[1], s64[1], [](float v) { return __shfl_xor(v, 16); });
        sg = (lane & 8) ? -1.0f : 1.0f;
        cstage(zr, zi, sg, c64[2], s64[2], [](float v) { return dppf<DPP_XOR8>(v); });
        sg = (lane & 4) ? -1.0f : 1.0f;
        cstage(zr, zi, sg, c64[3], s64[3], [](float v) { return __shfl_xor(v, 4); });
        sg = (lane & 2) ? -1.0f : 1.0f;
        cstage(zr, zi, sg, c64[4], s64[4], [](float v) { return dppf<DPP_XOR2>(v); });
        sg = (lane & 1) ? -1.0f : 1.0f;
        cstage(zr, zi, sg, c64[5], s64[5], [](float v) { return dppf<DPP_XOR1>(v); });
    }

    // ---- separation + magnitude + fused per-bin mel scatter ----
    const int k2 = (int)(__brev((unsigned)lane) >> 26);
    const int lp0 = (int)(__brev((unsigned)((64 - k2) & 63)) >> 26);
    #pragma unroll
    for (int p = 0; p < 2; ++p) {
        #pragma unroll
        for (int r = 0; r < 16; ++r) {
            float cx, cy;
            if (r == 0) { cx = __shfl(zr[p][0], lp0); cy = __shfl(zi[p][0], lp0); }
            else        { cx = __shfl_xor(zr[p][SIG[r]], 63); cy = __shfl_xor(zi[p][SIG[r]], 63); }
            const int k1 = BREV4[r];
            const int k = k2 * 16 + k1;
            if (k <= 512) {
                const float a = zr[p][r], b = zi[p][r];
                const float magA = sqrtf((a + cx) * (a + cx) + (b - cy) * (b - cy));
                const float magB = sqrtf((b + cy) * (b + cy) + (a - cx) * (a - cx));
                const int slot = (k & ~15) | (k1 ^ (k2 & 15));
                const float2 wt = wtab[slot];
                const float wu = wt.x;
                const float wd = wt.y;  // low 7 mantissa bits carry m1 (rel err ~1e-5)
                const int mp = (int)(__float_as_uint(wt.y) & 127u);
                const int mu = min(mp, 79);
                const int md = max(mp - 1, 0);
                atomicAdd(&smel[w][2*p  ][mu], magA * wu);
                atomicAdd(&smel[w][2*p  ][md], magA * wd);
                atomicAdd(&smel[w][2*p+1][mu], magB * wu);
                atomicAdd(&smel[w][2*p+1][md], magB * wd);
            }
        }
    }
    __syncthreads();

    // ---- coalesced transposed epilogue: 640 outputs, 5 per thread ----
    const int gb = blockIdx.x * 8;
    #pragma unroll
    for (int j = 0; j < 5; ++j) {
        const int t2 = tid + 128 * j;       // 0..639
        const int f8 = t2 & 7;
        const int m  = t2 >> 3;             // 0..79
        const unsigned g = (unsigned)(gb + f8);
        const unsigned bb = g / NUM_FRAMES;
        const unsigned ff = g - bb * NUM_FRAMES;
        out[((size_t)bb * N_MELS + m) * NUM_FRAMES + ff] = smel[f8 >> 2][f8 & 3][m];
    }
}

extern "C" void kernel_launch(void* const* d_in, const int* in_sizes, int n_in,
                              void* d_out, int out_size, void* d_ws, size_t ws_size,
                              hipStream_t stream) {
    const float* wav    = (const float*)d_in[0];
    const float* window = (const float*)d_in[1];
    const float* fb     = (const float*)d_in[2];
    const float* cosT   = (const float*)d_in[3];
    const float* sinT   = (const float*)d_in[4];
    float* out = (float*)d_out;

    const int blocks = TOTAL_FRAMES / 8;  // 2502: 2 waves/block, 4 frames/wave
    melspec_scatter_kernel<<<blocks, 128, 0, stream>>>(wav, window, fb, cosT, sinT, out);
}

// Round 6
// 53.578 us; speedup vs baseline: 2.7095x; 2.7095x over previous
//
#include <hip/hip_runtime.h>
#include <cstddef>

#define HOP 256
#define NSTFT 513
#define N_MELS 80
#define T_AUDIO 320000
#define NUM_FRAMES 1251
#define NBATCH 16
#define TOTAL_FRAMES (NBATCH * NUM_FRAMES)  // 20016 = 1251 blocks * 4 waves * 4 frames

// Slaney mel constants
#define LOGSTEP 0.06875177742094913f
#define MEL_MAX 45.24564047f
#define DF 15.625f

__device__ __forceinline__ int reflect_idx(int j) {
    j = (j < 0) ? -j : j;
    j = (j >= T_AUDIO) ? (2 * T_AUDIO - 2 - j) : j;
    return j;
}

// mel band index of bin k: m1 = floor(melq(k*DF)). Used identically for both
// the weight table and the band-boundary table -> self-consistent banding.
__device__ __forceinline__ int m1_of(int k) {
    const float f = k * DF;
    const float mel = (f < 1000.f) ? (3.0f / 200.0f) * f
                                   : 15.0f + logf(f * 1e-3f) * (1.0f / LOGSTEP);
    return (int)floorf(mel * (81.0f / MEL_MAX));
}

__device__ __forceinline__ int swz(int k) {  // conflict-breaking LDS slot
    return (k & ~15) | ((k ^ (k >> 4)) & 15);
}

// DPP cross-lane exchange (VALU pipe) for xor 1/2/8
#define DPP_XOR1 0xB1   // quad_perm [1,0,3,2]
#define DPP_XOR2 0x4E   // quad_perm [2,3,0,1]
#define DPP_XOR8 0x128  // row_ror:8
template<int CTRL>
__device__ __forceinline__ float dppf(float x) {
    return __int_as_float(__builtin_amdgcn_update_dpp(
        0, __float_as_int(x), CTRL, 0xF, 0xF, true));
}

template<class F>
__device__ __forceinline__ void cstage(float (&zr)[2][16], float (&zi)[2][16],
                                       float sg, float twr_, float twi_, F comm) {
    #pragma unroll
    for (int p = 0; p < 2; ++p) {
        #pragma unroll
        for (int r = 0; r < 16; ++r) {
            const float pr  = comm(zr[p][r]);
            const float pim = comm(zi[p][r]);
            const float qr = fmaf(sg, zr[p][r], pr);
            const float qi = fmaf(sg, zi[p][r], pim);
            zr[p][r] = fmaf(qr, twr_, -(qi * twi_));
            zi[p][r] = fmaf(qr, twi_, qi * twr_);
        }
    }
}

// 4 waves/block, 4 frames/wave (2 real-packed complex FFTs). Four-step
// 1024-pt FFT (16 regs x 64 lanes). Per PAIR: conjugate-symmetry separation
// -> magnitudes -> swizzled smag (one buffer, reused sequentially; wave-
// private, in-order DS) -> LDS-only mel matmul using a per-block 2-weight
// table wtab[k]=(fb[k][m1],fb[k][m1-1]) and band boundaries ks[m].
// Grid is fully co-resident (7 blocks/CU cap vs 4.9 needed) -> no tail.
__global__ __launch_bounds__(256) void melspec_sfft6_kernel(
    const float* __restrict__ wav,     // 16 x 320000
    const float* __restrict__ window,  // 1024
    const float* __restrict__ fb,      // 513 x 80
    const float* __restrict__ cosT,    // 1024 x 513 (row1 = cos(2pi j/1024))
    const float* __restrict__ sinT,    // 1024 x 513 (row1 = -sin(2pi j/1024))
    float* __restrict__ out)           // 16 x 80 x 1251
{
    __shared__ float2 smag[4][512];        // 16 KB, per-wave, reused per pair
    __shared__ float2 wtab[512];           // 4 KB  (wu, wd) per bin
    __shared__ unsigned short ks[84];      // band boundaries

    const int tid = threadIdx.x;
    const int lane = tid & 63;
    const int w = tid >> 6;
    const int g0 = (blockIdx.x * 4 + w) * 4;

    const int BREV4[16] = {0,8,4,12,2,10,6,14,1,9,5,13,3,11,7,15};
    const int SIG[16]   = {0,1,3,2,7,6,5,4,15,14,13,12,11,10,9,8};
    const float W16R[8] = {1.0f, 0.92387953251128674f, 0.70710678118654752f, 0.38268343236508977f,
                           0.0f, -0.38268343236508977f, -0.70710678118654752f, -0.92387953251128674f};
    const float W16I[8] = {0.0f, -0.38268343236508977f, -0.70710678118654752f, -0.92387953251128674f,
                           -1.0f, -0.92387953251128674f, -0.70710678118654752f, -0.38268343236508977f};

    // ---- per-block weight + band tables ----
    for (int k = tid + 1; k <= 512; k += 256) {
        const int mc = m1_of(k);
        const int mp = m1_of(k - 1);
        if (k <= 511) {
            const float wu = (mc <= 79) ? fb[k * N_MELS + mc] : 0.0f;
            const float wd = (mc >= 1 && mc <= 80) ? fb[k * N_MELS + mc - 1] : 0.0f;
            wtab[swz(k)] = make_float2(wu, wd);
        }
        for (int m = mp + 1; m <= mc; ++m) ks[m] = (unsigned short)k;
        if (k == 1) ks[0] = 1;
    }
    __syncthreads();

    unsigned bf0, ff0, bf3;
    {
        const unsigned g = (unsigned)g0;
        bf0 = g / NUM_FRAMES; ff0 = g - bf0 * NUM_FRAMES;
        bf3 = (unsigned)(g0 + 3) / NUM_FRAMES;
    }

    // ---- window ----
    float win[16];
    #pragma unroll
    for (int r = 0; r < 16; ++r) win[r] = window[r * 64 + lane];

    // ---- load 4 frames (75%-overlap shared-chunk fast path) ----
    float zr[2][16], zi[2][16];
    if (bf0 == bf3) {
        const float* wb = wav + (size_t)bf0 * T_AUDIO;
        const int base = (int)ff0 * HOP - 512;
        float ch[28];
        #pragma unroll
        for (int c = 0; c < 28; ++c)
            ch[c] = wb[reflect_idx(base + c * 64 + lane)];
        #pragma unroll
        for (int r = 0; r < 16; ++r) {
            zr[0][r] = ch[r]      * win[r];
            zi[0][r] = ch[r + 4]  * win[r];
            zr[1][r] = ch[r + 8]  * win[r];
            zi[1][r] = ch[r + 12] * win[r];
        }
    } else {
        #pragma unroll
        for (int fi = 0; fi < 4; ++fi) {
            const unsigned g = (unsigned)(g0 + fi);
            const unsigned bb = g / NUM_FRAMES;
            const unsigned ffr = g - bb * NUM_FRAMES;
            const float* wb = wav + (size_t)bb * T_AUDIO;
            const int base = (int)ffr * HOP - 512;
            #pragma unroll
            for (int r = 0; r < 16; ++r) {
                const float v = wb[reflect_idx(base + r * 64 + lane)] * win[r];
                if (fi == 0) zr[0][r] = v;
                else if (fi == 1) zi[0][r] = v;
                else if (fi == 2) zr[1][r] = v;
                else zi[1][r] = v;
            }
        }
    }

    const float* twc = cosT + NSTFT;  // row n=1
    const float* tws = sinT + NSTFT;

    // ---- cross twiddles: wk[k] = W_1024^(lane*k) via complex powers ----
    const float w1r = twc[lane];
    const float w1i = tws[lane];
    float wkr[16], wki[16];
    wkr[0] = 1.0f; wki[0] = 0.0f;
    #pragma unroll
    for (int k = 1; k < 16; ++k) {
        wkr[k] = wkr[k-1] * w1r - wki[k-1] * w1i;
        wki[k] = wkr[k-1] * w1i + wki[k-1] * w1r;
    }

    // ---- stage twiddles for cross-lane FFT ----
    float c64[6], s64[6];
    #pragma unroll
    for (int t = 0; t < 6; ++t) {
        const int half = 32 >> t;
        const bool hi = (lane & half) != 0;
        const int jj = (lane & (half - 1)) << (t + 4);
        c64[t] = hi ? twc[jj] : 1.0f;
        s64[t] = hi ? tws[jj] : 0.0f;
    }

    // ---- A) 16-pt DIF FFT in registers ----
    #define CBFLY(ar, ai, br, bi, wr, wi) { \
        const float _tr = (ar) - (br), _ti = (ai) - (bi); \
        (ar) += (br); (ai) += (bi); \
        (br) = _tr * (wr) - _ti * (wi); \
        (bi) = _tr * (wi) + _ti * (wr); }

    #pragma unroll
    for (int p = 0; p < 2; ++p) {
        #pragma unroll
        for (int q = 0; q < 8; ++q) CBFLY(zr[p][q], zi[p][q], zr[p][q+8], zi[p][q+8], W16R[q], W16I[q]);
        #pragma unroll
        for (int g = 0; g < 16; g += 8)
            #pragma unroll
            for (int q = 0; q < 4; ++q) CBFLY(zr[p][g+q], zi[p][g+q], zr[p][g+q+4], zi[p][g+q+4], W16R[2*q], W16I[2*q]);
        #pragma unroll
        for (int g = 0; g < 16; g += 4)
            #pragma unroll
            for (int q = 0; q < 2; ++q) CBFLY(zr[p][g+q], zi[p][g+q], zr[p][g+q+2], zi[p][g+q+2], W16R[4*q], W16I[4*q]);
        #pragma unroll
        for (int g = 0; g < 16; g += 2) CBFLY(zr[p][g], zi[p][g], zr[p][g+1], zi[p][g+1], 1.0f, 0.0f);
    }

    // ---- B) cross twiddle ----
    #pragma unroll
    for (int r = 1; r < 16; ++r) {
        const float c1 = wkr[BREV4[r]];
        const float s1 = wki[BREV4[r]];
        #pragma unroll
        for (int p = 0; p < 2; ++p) {
            const float xr = zr[p][r], xi = zi[p][r];
            zr[p][r] = xr * c1 - xi * s1;
            zi[p][r] = xr * s1 + xi * c1;
        }
    }

    // ---- C) 64-pt DIF FFT across lanes ----
    {
        float sg;
        sg = (lane & 32) ? -1.0f : 1.0f;
        cstage(zr, zi, sg, c64[0], s64[0], [](float v) { return __shfl_xor(v, 32); });
        sg = (lane & 16) ? -1.0f : 1.0f;
        cstage(zr, zi, sg, c64[1], s64[1], [](float v) { return __shfl_xor(v, 16); });
        sg = (lane & 8) ? -1.0f : 1.0f;
        cstage(zr, zi, sg, c64[2], s64[2], [](float v) { return dppf<DPP_XOR8>(v); });
        sg = (lane & 4) ? -1.0f : 1.0f;
        cstage(zr, zi, sg, c64[3], s64[3], [](float v) { return __shfl_xor(v, 4); });
        sg = (lane & 2) ? -1.0f : 1.0f;
        cstage(zr, zi, sg, c64[4], s64[4], [](float v) { return dppf<DPP_XOR2>(v); });
        sg = (lane & 1) ? -1.0f : 1.0f;
        cstage(zr, zi, sg, c64[5], s64[5], [](float v) { return dppf<DPP_XOR1>(v); });
    }

    // ---- per pair: separation + magnitude -> smag, then LDS-only mel ----
    const int k2 = (int)(__brev((unsigned)lane) >> 26);
    const int lp0 = (int)(__brev((unsigned)((64 - k2) & 63)) >> 26);
    #pragma unroll
    for (int p = 0; p < 2; ++p) {
        // separation + magnitude (stores only on lanes with k2 < 32, i.e. k <= 511)
        #pragma unroll
        for (int r = 0; r < 16; ++r) {
            float cx, cy;
            if (r == 0) { cx = __shfl(zr[p][0], lp0); cy = __shfl(zi[p][0], lp0); }
            else        { cx = __shfl_xor(zr[p][SIG[r]], 63); cy = __shfl_xor(zi[p][SIG[r]], 63); }
            const int k1 = BREV4[r];
            const int k = k2 * 16 + k1;
            if (k <= 511) {
                const float a = zr[p][r], b = zi[p][r];
                const float magA = 0.5f * sqrtf((a + cx) * (a + cx) + (b - cy) * (b - cy));
                const float magB = 0.5f * sqrtf((b + cy) * (b + cy) + (a - cx) * (a - cx));
                smag[w][(k & ~15) | (k1 ^ (k2 & 15))] = make_float2(magA, magB);
            }
        }
        // mel matmul for frames (g0+2p, g0+2p+1); wave-private smag, in-order DS
        #pragma unroll
        for (int i = 0; i < 3; ++i) {
            const int t2 = lane + 64 * i;
            if (t2 < 2 * N_MELS) {
                const int m = 79 - (t2 >> 1);      // descending width order
                const int fi = t2 & 1;
                const int ka = ks[m], kb = ks[m + 1], kc = ks[m + 2];
                float acc = 0.0f;
                for (int k = ka; k < kc; ++k) {
                    const int sl = swz(k);
                    const float2 mg = smag[w][sl];
                    const float2 wt = wtab[sl];
                    acc = fmaf(fi ? mg.y : mg.x, (k < kb) ? wt.x : wt.y, acc);
                }
                const unsigned g = (unsigned)(g0 + 2 * p + fi);
                const unsigned bb = g / NUM_FRAMES;
                const unsigned ff = g - bb * NUM_FRAMES;
                out[((size_t)bb * N_MELS + m) * NUM_FRAMES + ff] = acc;
            }
        }
    }
}

extern "C" void kernel_launch(void* const* d_in, const int* in_sizes, int n_in,
                              void* d_out, int out_size, void* d_ws, size_t ws_size,
                              hipStream_t stream) {
    const float* wav    = (const float*)d_in[0];
    const float* window = (const float*)d_in[1];
    const float* fb     = (const float*)d_in[2];
    const float* cosT   = (const float*)d_in[3];
    const float* sinT   = (const float*)d_in[4];
    float* out = (float*)d_out;

    const int blocks = TOTAL_FRAMES / 16;  // 1251: 4 waves/block, 4 frames/wave
    melspec_sfft6_kernel<<<blocks, 256, 0, stream>>>(wav, window, fb, cosT, sinT, out);
}